// Round 4
// baseline (348.624 us; speedup 1.0000x reference)
//
#include <hip/hip_runtime.h>
#include <hip/hip_cooperative_groups.h>
#include <math.h>

namespace cg = cooperative_groups;

#define BB 16
#define NN 65536
#define DD 24
#define KK 512
#define CH 32              // chunks per batch; grid = BB*CH = 512 blocks (2/CU — safe co-residency)
#define HPB (NN / CH)      // 2048 hits per chunk
#define TPB 256
#define RPB 16             // repulsion rows per block (CH*RPB == KK)

__device__ __forceinline__ float fixnum(float v) {
  return __builtin_isfinite(v) ? v : 0.0f;  // nan_to_num(nan=0, posinf=0, neginf=0)
}

// Full-block (256-thread) sum; returns total in ALL threads.
__device__ __forceinline__ float blockReduceSum(float v, float* sbuf) {
  __syncthreads();
  #pragma unroll
  for (int off = 32; off > 0; off >>= 1) v += __shfl_down(v, off, 64);
  int wid = threadIdx.x >> 6, lane = threadIdx.x & 63;
  if (lane == 0) sbuf[wid] = v;
  __syncthreads();
  return sbuf[0] + sbuf[1] + sbuf[2] + sbuf[3];
}

__global__ __launch_bounds__(TPB, 2) void fused_all(
    const float* __restrict__ beta, const int* __restrict__ sid,
    const int* __restrict__ iscp, const float* __restrict__ embed,
    float* __restrict__ cnt_p, float* __restrict__ den_p,
    float* __restrict__ cpc_p, float* __restrict__ cpl_p,
    int* __restrict__ first_p, float* __restrict__ marg_p,
    float* __restrict__ seg_cnt, float* __restrict__ loss_v,
    float* __restrict__ valid_f, float* __restrict__ has_cp_f,
    float* __restrict__ cpc_tot, float* __restrict__ cp_emb,
    float* __restrict__ d2_acc, float* __restrict__ rep_acc,
    float* __restrict__ out)
{
  cg::grid_group grid = cg::this_grid();
  __shared__ float s_cnt[KK], s_den[KK], s_cpc[KK], s_cpl[KK];
  __shared__ int   s_first[KK];
  __shared__ float s_d2[KK];
  __shared__ float sred[4];
  __shared__ float s_b[BB][5];

  int b = blockIdx.x / CH, c = blockIdx.x % CH, t = threadIdx.x;

  // ================= Phase 1: per-hit scan -> LDS segment partials =================
  for (int k = t; k < KK; k += TPB) {
    s_cnt[k] = 0.f; s_den[k] = 0.f; s_cpc[k] = 0.f; s_cpl[k] = 0.f; s_first[k] = NN;
  }
  __syncthreads();
  {
    int h0 = c * HPB + t * 8;               // 8 consecutive hits per thread
    size_t g0 = (size_t)b * NN + h0;
    float pm = 0.f, nm = 0.f;
    #pragma unroll
    for (int half = 0; half < 2; ++half) {
      size_t g = g0 + half * 4;
      float4 bv = *(const float4*)(beta + g);
      int4   sv = *(const int4*)(sid + g);
      int4   cv = *(const int4*)(iscp + g);
      float bs[4] = {bv.x, bv.y, bv.z, bv.w};
      int   ss[4] = {sv.x, sv.y, sv.z, sv.w};
      int   cs[4] = {cv.x, cv.y, cv.z, cv.w};
      #pragma unroll
      for (int j = 0; j < 4; ++j) {
        float bc = fminf(fmaxf(fixnum(bs[j]), -20.f), 20.f);
        float logit = bc * (1.0f / 0.7f);   // TAU
        int s = ss[j];
        atomicAdd(&s_cnt[s], 1.0f);
        atomicAdd(&s_den[s], __expf(logit)); // max-free denom (<=1.7e17, no overflow)
        float prob = 1.0f / (1.0f + __expf(-bc));
        if (cs[j] == 1) {
          atomicAdd(&s_cpc[s], 1.0f);
          atomicAdd(&s_cpl[s], logit);
          atomicMin(&s_first[s], h0 + half * 4 + j);
          pm += fmaxf(0.7f - prob, 0.f);    // THRESHOLD+MARGIN
        } else {
          nm += fmaxf(prob - 0.3f, 0.f);    // THRESHOLD-MARGIN
        }
      }
    }
    float pms = blockReduceSum(pm, sred);
    float nms = blockReduceSum(nm, sred);
    if (t == 0) { marg_p[2 * blockIdx.x] = pms; marg_p[2 * blockIdx.x + 1] = nms; }
    __syncthreads();
    size_t base = ((size_t)b * CH + c) * KK;
    for (int k = t; k < KK; k += TPB) {
      cnt_p[base + k] = s_cnt[k]; den_p[base + k] = s_den[k];
      cpc_p[base + k] = s_cpc[k]; cpl_p[base + k] = s_cpl[k];
      first_p[base + k] = s_first[k];
    }
  }
  grid.sync();

  // ======== Phase 2: reduce partials per (b,k); gather cp_emb; zero accum ========
  {
    int sub = t >> 4, lane16 = t & 15;
    int idx = blockIdx.x * 16 + sub;        // 512*16 == BB*KK
    int pb = idx >> 9, pk = idx & (KK - 1);
    size_t base0 = ((size_t)pb * CH + lane16) * KK + pk;
    size_t base1 = ((size_t)pb * CH + lane16 + 16) * KK + pk;
    float cnt = cnt_p[base0] + cnt_p[base1];
    float den = den_p[base0] + den_p[base1];
    float cpc = cpc_p[base0] + cpc_p[base1];
    float cpl = cpl_p[base0] + cpl_p[base1];
    int fc = min(first_p[base0], first_p[base1]);
    #pragma unroll
    for (int m = 8; m > 0; m >>= 1) {       // butterfly: every lane gets totals
      cnt += __shfl_xor(cnt, m, 16);
      den += __shfl_xor(den, m, 16);
      cpc += __shfl_xor(cpc, m, 16);
      cpl += __shfl_xor(cpl, m, 16);
      fc = min(fc, __shfl_xor(fc, m, 16));
    }
    if (lane16 == 0) {
      bool present = cnt > 0.f;
      bool vinst = present && (cpc == 1.0f);
      float p = __expf(cpl) / fmaxf(den, 1e-30f);
      seg_cnt[idx] = cnt;
      cpc_tot[idx] = cpc;
      loss_v[idx] = vinst ? -__logf(p + 1e-9f) : 0.f;
      valid_f[idx] = vinst ? 1.f : 0.f;
      has_cp_f[idx] = ((fc < NN) && present) ? 1.f : 0.f;
      d2_acc[idx] = 0.f;
      if (idx < BB) rep_acc[idx] = 0.f;
    }
    int row = fc < NN ? fc : NN - 1;
    if (lane16 < DD / 4) {
      const float4* src = (const float4*)(embed + ((size_t)pb * NN + row) * DD);
      float4 v = src[lane16];
      v.x = fixnum(v.x); v.y = fixnum(v.y); v.z = fixnum(v.z); v.w = fixnum(v.w);
      ((float4*)(cp_emb + (size_t)idx * DD))[lane16] = v;
    }
  }
  grid.sync();

  // ============ Phase 3: attraction scan (100 MB embed pass) + repulsion ============
  {
    for (int k = t; k < KK; k += TPB) s_d2[k] = 0.f;
    __syncthreads();
    const float* cebase = cp_emb + (size_t)b * KK * DD;
    #pragma unroll
    for (int i = 0; i < HPB / TPB; ++i) {
      int h = c * HPB + i * TPB + t;
      size_t g = (size_t)b * NN + h;
      int s = sid[g];
      const float4* e  = (const float4*)(embed + g * DD);
      const float4* ce = (const float4*)(cebase + (size_t)s * DD);  // L1/L2-hot
      float d2 = 0.f;
      #pragma unroll
      for (int q = 0; q < DD / 4; ++q) {
        float4 ev = e[q]; float4 cv = ce[q];
        float x;
        x = fixnum(ev.x) - cv.x; d2 += x * x;
        x = fixnum(ev.y) - cv.y; d2 += x * x;
        x = fixnum(ev.z) - cv.z; d2 += x * x;
        x = fixnum(ev.w) - cv.w; d2 += x * x;
      }
      atomicAdd(&s_d2[s], fminf(d2, 50.f));
    }
    __syncthreads();
    for (int k = t; k < KK; k += TPB)
      atomicAdd(&d2_acc[b * KK + k], s_d2[k]);   // 32 adds/address device-wide

    // repulsion: rows c*RPB..+RPB, cols j0=t, j1=t+TPB
    int j0 = t, j1 = t + TPB;
    float cj0[DD], cj1[DD];
    const float4* cj0p = (const float4*)(cebase + (size_t)j0 * DD);
    const float4* cj1p = (const float4*)(cebase + (size_t)j1 * DD);
    #pragma unroll
    for (int q = 0; q < DD / 4; ++q) {
      float4 a = cj0p[q], bq = cj1p[q];
      cj0[q*4] = a.x; cj0[q*4+1] = a.y; cj0[q*4+2] = a.z; cj0[q*4+3] = a.w;
      cj1[q*4] = bq.x; cj1[q*4+1] = bq.y; cj1[q*4+2] = bq.z; cj1[q*4+3] = bq.w;
    }
    float m0 = has_cp_f[b * KK + j0], m1 = has_cp_f[b * KK + j1];
    float acc = 0.f;
    #pragma unroll
    for (int ri = 0; ri < RPB; ++ri) {
      int i = c * RPB + ri;
      float mi = has_cp_f[b * KK + i];          // uniform -> broadcast
      float d20 = 0.f, d21 = 0.f;
      #pragma unroll
      for (int d = 0; d < DD; ++d) {
        float ci = cebase[i * DD + d];          // uniform -> broadcast
        float x0 = ci - cj0[d]; d20 += x0 * x0;
        float x1 = ci - cj1[d]; d21 += x1 * x1;
      }
      acc += mi * (m0 * __expf(-fminf(d20, 50.f)) + m1 * __expf(-fminf(d21, 50.f)));
    }
    float tot = blockReduceSum(acc, sred);
    if (t == 0) atomicAdd(&rep_acc[b], tot);
  }
  grid.sync();

  // ========================= Phase 4: final (block 0 only) =========================
  if (blockIdx.x == 0) {
    int w = t >> 6, l = t & 63;
    #pragma unroll
    for (int bb = 0; bb < 4; ++bb) {
      int fb = w * 4 + bb;                  // wave w handles batches 4w..4w+3
      float attr = 0.f, ce = 0.f, vcnt = 0.f, pcnt = 0.f, mcnt = 0.f;
      #pragma unroll
      for (int k = l; k < KK; k += 64) {
        int idx = fb * KK + k;
        float hc = has_cp_f[idx];
        attr += hc * (d2_acc[idx] / fmaxf(seg_cnt[idx], 1.f));
        ce   += loss_v[idx];
        vcnt += valid_f[idx];
        pcnt += cpc_tot[idx];
        mcnt += hc;
      }
      float pm = (l < CH) ? marg_p[(fb * CH + l) * 2]     : 0.f;
      float nm = (l < CH) ? marg_p[(fb * CH + l) * 2 + 1] : 0.f;
      #pragma unroll
      for (int off = 32; off > 0; off >>= 1) {
        attr += __shfl_down(attr, off, 64);
        ce   += __shfl_down(ce, off, 64);
        vcnt += __shfl_down(vcnt, off, 64);
        pcnt += __shfl_down(pcnt, off, 64);
        mcnt += __shfl_down(mcnt, off, 64);
        pm   += __shfl_down(pm, off, 64);
        nm   += __shfl_down(nm, off, 64);
      }
      if (l == 0) {
        float pos = pcnt, neg = (float)NN - pos;
        float slice_ce = ce / fmaxf(vcnt, 1.f);
        float beta_loss = slice_ce + 5.0f * (pm / fmaxf(pos, 1.f) + nm / fmaxf(neg, 1.f));
        float rep = rep_acc[fb] / fmaxf(mcnt * mcnt, 1.f);
        float repulsion = (mcnt > 1.f) ? 1.5f * rep : 0.f;
        float v = (pos >= 1.f && neg >= 1.f && vcnt > 0.f) ? 1.f : 0.f;
        s_b[fb][0] = (beta_loss + attr + repulsion) * v;
        s_b[fb][1] = beta_loss * v;
        s_b[fb][2] = attr * v;
        s_b[fb][3] = repulsion * v;
        s_b[fb][4] = v;
      }
    }
    __syncthreads();
    if (t == 0) {
      float s0 = 0.f, s1 = 0.f, s2 = 0.f, s3 = 0.f, cv = 0.f;
      #pragma unroll
      for (int i = 0; i < BB; ++i) {
        s0 += s_b[i][0]; s1 += s_b[i][1]; s2 += s_b[i][2]; s3 += s_b[i][3]; cv += s_b[i][4];
      }
      float safe = fmaxf(cv, 1.f);
      bool ok = cv > 0.f;
      out[0] = ok ? s0 / safe : 0.f;
      out[1] = ok ? s1 / safe : 0.f;
      out[2] = ok ? s2 / safe : 0.f;
      out[3] = ok ? s3 / safe : 0.f;
    }
  }
}

extern "C" void kernel_launch(void* const* d_in, const int* in_sizes, int n_in,
                              void* d_out, int out_size, void* d_ws, size_t ws_size,
                              hipStream_t stream) {
  (void)in_sizes; (void)n_in; (void)out_size; (void)ws_size;
  const float* beta  = (const float*)d_in[0];
  const float* embed = (const float*)d_in[1];
  const int*   sid   = (const int*)d_in[2];
  const int*   iscp  = (const int*)d_in[3];
  float* out = (float*)d_out;
  char* ws = (char*)d_ws;

  size_t off = 0;
  auto alloc = [&](size_t bytes) {
    size_t o = off; off += (bytes + 255) & ~(size_t)255; return o;
  };
  const size_t BCK = (size_t)BB * CH * KK * 4;   // 1 MB partial arrays
  const size_t BKf = (size_t)BB * KK * 4;        // 32 KB
  size_t o_cnt_p  = alloc(BCK);
  size_t o_den_p  = alloc(BCK);
  size_t o_cpc_p  = alloc(BCK);
  size_t o_cpl_p  = alloc(BCK);
  size_t o_first  = alloc(BCK);
  size_t o_marg   = alloc((size_t)BB * CH * 2 * 4);
  size_t o_segc   = alloc(BKf);
  size_t o_lossv  = alloc(BKf);
  size_t o_validf = alloc(BKf);
  size_t o_hascp  = alloc(BKf);
  size_t o_cpct   = alloc(BKf);
  size_t o_d2     = alloc(BKf);
  size_t o_cpe    = alloc((size_t)BB * KK * DD * 4);
  size_t o_rep    = alloc((size_t)BB * 4);

  float* p_cnt  = (float*)(ws + o_cnt_p);
  float* p_den  = (float*)(ws + o_den_p);
  float* p_cpc  = (float*)(ws + o_cpc_p);
  float* p_cpl  = (float*)(ws + o_cpl_p);
  int*   p_fst  = (int*)(ws + o_first);
  float* p_marg = (float*)(ws + o_marg);
  float* p_segc = (float*)(ws + o_segc);
  float* p_lv   = (float*)(ws + o_lossv);
  float* p_vf   = (float*)(ws + o_validf);
  float* p_hc   = (float*)(ws + o_hascp);
  float* p_cpt  = (float*)(ws + o_cpct);
  float* p_cpe  = (float*)(ws + o_cpe);
  float* p_d2   = (float*)(ws + o_d2);
  float* p_rep  = (float*)(ws + o_rep);

  void* args[] = {
    (void*)&beta, (void*)&sid, (void*)&iscp, (void*)&embed,
    (void*)&p_cnt, (void*)&p_den, (void*)&p_cpc, (void*)&p_cpl,
    (void*)&p_fst, (void*)&p_marg,
    (void*)&p_segc, (void*)&p_lv, (void*)&p_vf, (void*)&p_hc,
    (void*)&p_cpt, (void*)&p_cpe, (void*)&p_d2, (void*)&p_rep,
    (void*)&out,
  };
  hipLaunchCooperativeKernel((const void*)fused_all, dim3(BB * CH), dim3(TPB),
                             args, 0, stream);
}

// Round 5
// 241.624 us; speedup vs baseline: 1.4428x; 1.4428x over previous
//
#include <hip/hip_runtime.h>
#include <math.h>

#define BB 16
#define NN 65536
#define DD 24
#define KK 512
#define CH1 32             // k1 chunks per batch (512 blocks)
#define HPB1 (NN / CH1)    // 2048 hits per k1 block
#define CH3 64             // k3 chunks per batch (1024 blocks)
#define HPB3 (NN / CH3)    // 1024 hits per k3 block
#define TPB 256
#define RPB 8              // repulsion rows per k3 block (CH3*RPB == KK)

__device__ __forceinline__ float fixnum(float v) {
  return __builtin_isfinite(v) ? v : 0.0f;  // nan_to_num(nan=0, posinf=0, neginf=0)
}

__device__ __forceinline__ float blockReduceSum(float v, float* sbuf) {
  __syncthreads();
  #pragma unroll
  for (int off = 32; off > 0; off >>= 1) v += __shfl_down(v, off, 64);
  int wid = threadIdx.x >> 6, lane = threadIdx.x & 63;
  if (lane == 0) sbuf[wid] = v;
  __syncthreads();
  return sbuf[0] + sbuf[1] + sbuf[2] + sbuf[3];
}

// ---- K1: per-hit scan -> LDS segment partials (512 blocks, 8 hits/thread) ----
__global__ __launch_bounds__(TPB) void k1_seg(
    const float* __restrict__ beta, const int* __restrict__ sid,
    const int* __restrict__ iscp,
    float* __restrict__ cnt_p, float* __restrict__ den_p,
    float* __restrict__ cpc_p, float* __restrict__ cpl_p,
    int* __restrict__ first_p, float* __restrict__ marg_p)
{
  __shared__ float s_cnt[KK], s_den[KK], s_cpc[KK], s_cpl[KK];
  __shared__ int   s_first[KK];
  __shared__ float sred[4];
  int b = blockIdx.x / CH1, c = blockIdx.x % CH1, t = threadIdx.x;
  for (int k = t; k < KK; k += TPB) {
    s_cnt[k] = 0.f; s_den[k] = 0.f; s_cpc[k] = 0.f; s_cpl[k] = 0.f; s_first[k] = NN;
  }
  __syncthreads();
  int h0 = c * HPB1 + t * 8;                // 8 consecutive hits per thread
  size_t g0 = (size_t)b * NN + h0;
  float pm = 0.f, nm = 0.f;
  #pragma unroll
  for (int half = 0; half < 2; ++half) {
    size_t g = g0 + half * 4;
    float4 bv = *(const float4*)(beta + g);
    int4   sv = *(const int4*)(sid + g);
    int4   cv = *(const int4*)(iscp + g);
    float bs[4] = {bv.x, bv.y, bv.z, bv.w};
    int   ss[4] = {sv.x, sv.y, sv.z, sv.w};
    int   cs[4] = {cv.x, cv.y, cv.z, cv.w};
    #pragma unroll
    for (int j = 0; j < 4; ++j) {
      float bc = fminf(fmaxf(fixnum(bs[j]), -20.f), 20.f);
      float logit = bc * (1.0f / 0.7f);     // TAU
      int s = ss[j];
      atomicAdd(&s_cnt[s], 1.0f);
      atomicAdd(&s_den[s], __expf(logit));  // max-free denom (<=1.7e17, no overflow)
      float prob = 1.0f / (1.0f + __expf(-bc));
      if (cs[j] == 1) {
        atomicAdd(&s_cpc[s], 1.0f);
        atomicAdd(&s_cpl[s], logit);
        atomicMin(&s_first[s], h0 + half * 4 + j);
        pm += fmaxf(0.7f - prob, 0.f);      // THRESHOLD+MARGIN
      } else {
        nm += fmaxf(prob - 0.3f, 0.f);      // THRESHOLD-MARGIN
      }
    }
  }
  float pms = blockReduceSum(pm, sred);
  float nms = blockReduceSum(nm, sred);
  if (t == 0) { marg_p[2 * blockIdx.x] = pms; marg_p[2 * blockIdx.x + 1] = nms; }
  __syncthreads();
  size_t base = ((size_t)b * CH1 + c) * KK;
  for (int k = t; k < KK; k += TPB) {
    cnt_p[base + k] = s_cnt[k]; den_p[base + k] = s_den[k];
    cpc_p[base + k] = s_cpc[k]; cpl_p[base + k] = s_cpl[k];
    first_p[base + k] = s_first[k];
  }
}

// ---- K2: reduce partials per (b,k); gather cp_emb; zero accumulators+ticket ----
__global__ __launch_bounds__(TPB) void k2_fin(
    const float* __restrict__ embed,
    const float* __restrict__ cnt_p, const float* __restrict__ den_p,
    const float* __restrict__ cpc_p, const float* __restrict__ cpl_p,
    const int* __restrict__ first_p,
    float* __restrict__ seg_cnt, float* __restrict__ loss_v,
    float* __restrict__ valid_f, float* __restrict__ has_cp_f,
    float* __restrict__ cpc_tot, float* __restrict__ cp_emb,
    float* __restrict__ d2_acc, float* __restrict__ rep_acc,
    unsigned* __restrict__ done)
{
  int idx = blockIdx.x * TPB + threadIdx.x;   // 0 .. BB*KK-1
  int b = idx >> 9, k = idx & (KK - 1);
  float cnt = 0.f, den = 0.f, cpc = 0.f, cpl = 0.f;
  int fc = NN;
  #pragma unroll 8
  for (int c = 0; c < CH1; ++c) {
    size_t base = ((size_t)b * CH1 + c) * KK + k;   // coalesced across threads
    cnt += cnt_p[base]; den += den_p[base];
    cpc += cpc_p[base]; cpl += cpl_p[base];
    fc = min(fc, first_p[base]);
  }
  bool present = cnt > 0.f;
  bool vinst = present && (cpc == 1.0f);
  float p = __expf(cpl) / fmaxf(den, 1e-30f);
  seg_cnt[idx] = cnt;
  cpc_tot[idx] = cpc;
  loss_v[idx] = vinst ? -__logf(p + 1e-9f) : 0.f;
  valid_f[idx] = vinst ? 1.f : 0.f;
  has_cp_f[idx] = ((fc < NN) && present) ? 1.f : 0.f;
  d2_acc[idx] = 0.f;
  if (idx < BB) rep_acc[idx] = 0.f;
  if (idx == 0) *done = 0u;
  int row = fc < NN ? fc : NN - 1;
  const float4* src = (const float4*)(embed + ((size_t)b * NN + row) * DD);
  float4* dst = (float4*)(cp_emb + (size_t)idx * DD);
  #pragma unroll
  for (int q = 0; q < DD / 4; ++q) {
    float4 v = src[q];
    v.x = fixnum(v.x); v.y = fixnum(v.y); v.z = fixnum(v.z); v.w = fixnum(v.w);
    dst[q] = v;
  }
}

// ---- K3: attraction scan (4 hits/thread, 1 sid load) + repulsion + last-block final ----
__global__ __launch_bounds__(TPB) void k3_attr_rep_fin(
    const float* __restrict__ embed, const int* __restrict__ sid,
    const float* __restrict__ cp_emb, const float* __restrict__ has_cp_f,
    const float* __restrict__ seg_cnt, const float* __restrict__ loss_v,
    const float* __restrict__ valid_f, const float* __restrict__ cpc_tot,
    const float* __restrict__ marg_p,
    float* __restrict__ d2_acc, float* __restrict__ rep_acc,
    unsigned* __restrict__ done, float* __restrict__ out)
{
  __shared__ float s_d2[KK];
  __shared__ float sred[4];
  __shared__ float s_b[BB][5];
  __shared__ int amLast;
  int b = blockIdx.x / CH3, c = blockIdx.x % CH3, t = threadIdx.x;
  for (int k = t; k < KK; k += TPB) s_d2[k] = 0.f;
  __syncthreads();
  const float* cebase = cp_emb + (size_t)b * KK * DD;
  {
    int h0 = c * HPB3 + t * 4;              // 4 consecutive hits per thread
    size_t g0 = (size_t)b * NN + h0;
    int4 sv = *(const int4*)(sid + g0);     // ONE sid load for all 4 hits
    int ss[4] = {sv.x, sv.y, sv.z, sv.w};
    #pragma unroll
    for (int j = 0; j < 4; ++j) {
      const float4* e  = (const float4*)(embed + (g0 + j) * DD);
      const float4* ce = (const float4*)(cebase + (size_t)ss[j] * DD);
      float d2 = 0.f;
      #pragma unroll
      for (int q = 0; q < DD / 4; ++q) {
        float4 ev = e[q]; float4 cv = ce[q];
        float x;
        x = fixnum(ev.x) - cv.x; d2 += x * x;
        x = fixnum(ev.y) - cv.y; d2 += x * x;
        x = fixnum(ev.z) - cv.z; d2 += x * x;
        x = fixnum(ev.w) - cv.w; d2 += x * x;
      }
      atomicAdd(&s_d2[ss[j]], fminf(d2, 50.f));
    }
  }
  __syncthreads();
  for (int k = t; k < KK; k += TPB)
    atomicAdd(&d2_acc[b * KK + k], s_d2[k]);   // device-scope, coherent point

  // --- repulsion: rows c*RPB..+RPB, cols j0=t, j1=t+TPB ---
  {
    int j0 = t, j1 = t + TPB;
    float cj0[DD], cj1[DD];
    const float4* cj0p = (const float4*)(cebase + (size_t)j0 * DD);
    const float4* cj1p = (const float4*)(cebase + (size_t)j1 * DD);
    #pragma unroll
    for (int q = 0; q < DD / 4; ++q) {
      float4 a = cj0p[q], bq = cj1p[q];
      cj0[q*4] = a.x; cj0[q*4+1] = a.y; cj0[q*4+2] = a.z; cj0[q*4+3] = a.w;
      cj1[q*4] = bq.x; cj1[q*4+1] = bq.y; cj1[q*4+2] = bq.z; cj1[q*4+3] = bq.w;
    }
    float m0 = has_cp_f[b * KK + j0], m1 = has_cp_f[b * KK + j1];
    float acc = 0.f;
    #pragma unroll
    for (int ri = 0; ri < RPB; ++ri) {
      int i = c * RPB + ri;
      float mi = has_cp_f[b * KK + i];        // uniform -> broadcast
      float d20 = 0.f, d21 = 0.f;
      #pragma unroll
      for (int d = 0; d < DD; ++d) {
        float ci = cebase[i * DD + d];        // uniform -> broadcast
        float x0 = ci - cj0[d]; d20 += x0 * x0;
        float x1 = ci - cj1[d]; d21 += x1 * x1;
      }
      acc += mi * (m0 * __expf(-fminf(d20, 50.f)) + m1 * __expf(-fminf(d21, 50.f)));
    }
    float tot = blockReduceSum(acc, sred);
    if (t == 0) atomicAdd(&rep_acc[b], tot);
  }

  // --- last-block finalize (atomic ticket) ---
  __syncthreads();                            // all waves' atomics retired (vmcnt drained)
  if (t == 0) {
    __threadfence();                          // order our atomics before the ticket
    unsigned old = atomicAdd(done, 1u);
    amLast = (old == (unsigned)(BB * CH3 - 1));
  }
  __syncthreads();
  if (amLast) {
    __threadfence();                          // acquire
    int w = t >> 6, l = t & 63;               // 4 waves x 4 batches each
    #pragma unroll
    for (int bb = 0; bb < 4; ++bb) {
      int fb = w * 4 + bb;
      float attr = 0.f, ce = 0.f, vcnt = 0.f, pcnt = 0.f, mcnt = 0.f;
      #pragma unroll
      for (int k = l; k < KK; k += 64) {
        int idx = fb * KK + k;
        float hc = has_cp_f[idx];
        float dv = __hip_atomic_load(&d2_acc[idx], __ATOMIC_RELAXED,
                                     __HIP_MEMORY_SCOPE_AGENT);
        attr += hc * (dv / fmaxf(seg_cnt[idx], 1.f));
        ce   += loss_v[idx];
        vcnt += valid_f[idx];
        pcnt += cpc_tot[idx];
        mcnt += hc;
      }
      float pm = (l < CH1) ? marg_p[(fb * CH1 + l) * 2]     : 0.f;
      float nm = (l < CH1) ? marg_p[(fb * CH1 + l) * 2 + 1] : 0.f;
      #pragma unroll
      for (int off = 32; off > 0; off >>= 1) {
        attr += __shfl_down(attr, off, 64);
        ce   += __shfl_down(ce, off, 64);
        vcnt += __shfl_down(vcnt, off, 64);
        pcnt += __shfl_down(pcnt, off, 64);
        mcnt += __shfl_down(mcnt, off, 64);
        pm   += __shfl_down(pm, off, 64);
        nm   += __shfl_down(nm, off, 64);
      }
      if (l == 0) {
        float pos = pcnt, neg = (float)NN - pos;
        float slice_ce = ce / fmaxf(vcnt, 1.f);
        float beta_loss = slice_ce + 5.0f * (pm / fmaxf(pos, 1.f) + nm / fmaxf(neg, 1.f));
        float repv = __hip_atomic_load(&rep_acc[fb], __ATOMIC_RELAXED,
                                       __HIP_MEMORY_SCOPE_AGENT);
        float rep = repv / fmaxf(mcnt * mcnt, 1.f);
        float repulsion = (mcnt > 1.f) ? 1.5f * rep : 0.f;
        float v = (pos >= 1.f && neg >= 1.f && vcnt > 0.f) ? 1.f : 0.f;
        s_b[fb][0] = (beta_loss + attr + repulsion) * v;
        s_b[fb][1] = beta_loss * v;
        s_b[fb][2] = attr * v;
        s_b[fb][3] = repulsion * v;
        s_b[fb][4] = v;
      }
    }
    __syncthreads();
    if (t == 0) {
      float s0 = 0.f, s1 = 0.f, s2 = 0.f, s3 = 0.f, cv = 0.f;
      #pragma unroll
      for (int i = 0; i < BB; ++i) {
        s0 += s_b[i][0]; s1 += s_b[i][1]; s2 += s_b[i][2]; s3 += s_b[i][3]; cv += s_b[i][4];
      }
      float safe = fmaxf(cv, 1.f);
      bool ok = cv > 0.f;
      out[0] = ok ? s0 / safe : 0.f;
      out[1] = ok ? s1 / safe : 0.f;
      out[2] = ok ? s2 / safe : 0.f;
      out[3] = ok ? s3 / safe : 0.f;
    }
  }
}

extern "C" void kernel_launch(void* const* d_in, const int* in_sizes, int n_in,
                              void* d_out, int out_size, void* d_ws, size_t ws_size,
                              hipStream_t stream) {
  (void)in_sizes; (void)n_in; (void)out_size; (void)ws_size;
  const float* beta  = (const float*)d_in[0];
  const float* embed = (const float*)d_in[1];
  const int*   sid   = (const int*)d_in[2];
  const int*   iscp  = (const int*)d_in[3];
  float* out = (float*)d_out;
  char* ws = (char*)d_ws;

  size_t off = 0;
  auto alloc = [&](size_t bytes) {
    size_t o = off; off += (bytes + 255) & ~(size_t)255; return o;
  };
  const size_t BCK = (size_t)BB * CH1 * KK * 4;  // 1 MB partial arrays
  const size_t BKf = (size_t)BB * KK * 4;        // 32 KB
  size_t o_cnt_p  = alloc(BCK);
  size_t o_den_p  = alloc(BCK);
  size_t o_cpc_p  = alloc(BCK);
  size_t o_cpl_p  = alloc(BCK);
  size_t o_first  = alloc(BCK);
  size_t o_marg   = alloc((size_t)BB * CH1 * 2 * 4);
  size_t o_segc   = alloc(BKf);
  size_t o_lossv  = alloc(BKf);
  size_t o_validf = alloc(BKf);
  size_t o_hascp  = alloc(BKf);
  size_t o_cpct   = alloc(BKf);
  size_t o_d2     = alloc(BKf);
  size_t o_cpe    = alloc((size_t)BB * KK * DD * 4);
  size_t o_rep    = alloc((size_t)BB * 4);
  size_t o_done   = alloc(256);

  k1_seg<<<BB * CH1, TPB, 0, stream>>>(beta, sid, iscp,
      (float*)(ws + o_cnt_p), (float*)(ws + o_den_p),
      (float*)(ws + o_cpc_p), (float*)(ws + o_cpl_p),
      (int*)(ws + o_first), (float*)(ws + o_marg));

  k2_fin<<<(BB * KK) / TPB, TPB, 0, stream>>>(embed,
      (const float*)(ws + o_cnt_p), (const float*)(ws + o_den_p),
      (const float*)(ws + o_cpc_p), (const float*)(ws + o_cpl_p),
      (const int*)(ws + o_first),
      (float*)(ws + o_segc), (float*)(ws + o_lossv), (float*)(ws + o_validf),
      (float*)(ws + o_hascp), (float*)(ws + o_cpct), (float*)(ws + o_cpe),
      (float*)(ws + o_d2), (float*)(ws + o_rep), (unsigned*)(ws + o_done));

  k3_attr_rep_fin<<<BB * CH3, TPB, 0, stream>>>(embed, sid,
      (const float*)(ws + o_cpe), (const float*)(ws + o_hascp),
      (const float*)(ws + o_segc), (const float*)(ws + o_lossv),
      (const float*)(ws + o_validf), (const float*)(ws + o_cpct),
      (const float*)(ws + o_marg),
      (float*)(ws + o_d2), (float*)(ws + o_rep),
      (unsigned*)(ws + o_done), out);
}

// Round 6
// 201.797 us; speedup vs baseline: 1.7276x; 1.1974x over previous
//
#include <hip/hip_runtime.h>
#include <math.h>

#define BB 16
#define NN 65536
#define DD 24
#define KK 512
#define CH 64              // chunks per batch for k1/k3 (1024 blocks each)
#define HPB (NN / CH)      // 1024 hits per chunk
#define TPB 256
#define RPB 8              // repulsion rows per k3 block (CH*RPB == KK)

__device__ __forceinline__ float fixnum(float v) {
  return __builtin_isfinite(v) ? v : 0.0f;  // nan_to_num(nan=0, posinf=0, neginf=0)
}

__device__ __forceinline__ float blockReduceSum(float v, float* sbuf) {
  __syncthreads();
  #pragma unroll
  for (int off = 32; off > 0; off >>= 1) v += __shfl_down(v, off, 64);
  int wid = threadIdx.x >> 6, lane = threadIdx.x & 63;
  if (lane == 0) sbuf[wid] = v;
  __syncthreads();
  return sbuf[0] + sbuf[1] + sbuf[2] + sbuf[3];
}

// ---- K1: per-hit scan -> LDS segment partials (1024 blocks, 4 hits/thread) ----
__global__ __launch_bounds__(TPB) void k1_seg(
    const float* __restrict__ beta, const int* __restrict__ sid,
    const int* __restrict__ iscp,
    float* __restrict__ cnt_p, float* __restrict__ den_p,
    float* __restrict__ cpc_p, float* __restrict__ cpl_p,
    int* __restrict__ first_p, float* __restrict__ marg_p)
{
  __shared__ float s_cnt[KK], s_den[KK], s_cpc[KK], s_cpl[KK];
  __shared__ int   s_first[KK];
  __shared__ float sred[4];
  int b = blockIdx.x >> 6, c = blockIdx.x & 63, t = threadIdx.x;
  for (int k = t; k < KK; k += TPB) {
    s_cnt[k] = 0.f; s_den[k] = 0.f; s_cpc[k] = 0.f; s_cpl[k] = 0.f; s_first[k] = NN;
  }
  __syncthreads();
  int h0 = c * HPB + t * 4;                 // 4 consecutive hits per thread
  size_t g0 = (size_t)b * NN + h0;
  float4 bv = *(const float4*)(beta + g0);
  int4   sv = *(const int4*)(sid + g0);
  int4   cv = *(const int4*)(iscp + g0);
  float pm = 0.f, nm = 0.f;
  float bs[4] = {bv.x, bv.y, bv.z, bv.w};
  int   ss[4] = {sv.x, sv.y, sv.z, sv.w};
  int   cs[4] = {cv.x, cv.y, cv.z, cv.w};
  #pragma unroll
  for (int j = 0; j < 4; ++j) {
    float bc = fminf(fmaxf(fixnum(bs[j]), -20.f), 20.f);
    float logit = bc * (1.0f / 0.7f);       // TAU
    int s = ss[j];
    atomicAdd(&s_cnt[s], 1.0f);
    atomicAdd(&s_den[s], __expf(logit));    // max-free denom (<=1.7e17, no overflow)
    float prob = 1.0f / (1.0f + __expf(-bc));
    if (cs[j] == 1) {
      atomicAdd(&s_cpc[s], 1.0f);
      atomicAdd(&s_cpl[s], logit);
      atomicMin(&s_first[s], h0 + j);
      pm += fmaxf(0.7f - prob, 0.f);        // THRESHOLD+MARGIN
    } else {
      nm += fmaxf(prob - 0.3f, 0.f);        // THRESHOLD-MARGIN
    }
  }
  float pms = blockReduceSum(pm, sred);
  float nms = blockReduceSum(nm, sred);
  if (t == 0) { marg_p[2 * blockIdx.x] = pms; marg_p[2 * blockIdx.x + 1] = nms; }
  __syncthreads();
  size_t base = ((size_t)b * CH + c) * KK;
  for (int k = t; k < KK; k += TPB) {
    cnt_p[base + k] = s_cnt[k]; den_p[base + k] = s_den[k];
    cpc_p[base + k] = s_cpc[k]; cpl_p[base + k] = s_cpl[k];
    first_p[base + k] = s_first[k];
  }
}

// ---- K2: reduce partials per (b,k); gather cp_emb; zero accumulators+ticket ----
__global__ __launch_bounds__(TPB) void k2_fin(
    const float* __restrict__ embed,
    const float* __restrict__ cnt_p, const float* __restrict__ den_p,
    const float* __restrict__ cpc_p, const float* __restrict__ cpl_p,
    const int* __restrict__ first_p,
    float* __restrict__ seg_cnt, float* __restrict__ loss_v,
    float* __restrict__ valid_f, float* __restrict__ has_cp_f,
    float* __restrict__ cpc_tot, float* __restrict__ cp_emb,
    float* __restrict__ d2_acc, float* __restrict__ rep_acc,
    unsigned* __restrict__ done)
{
  int idx = blockIdx.x * TPB + threadIdx.x;   // 0 .. BB*KK-1
  int b = idx >> 9, k = idx & (KK - 1);
  float cnt = 0.f, den = 0.f, cpc = 0.f, cpl = 0.f;
  int fc = NN;
  #pragma unroll 8
  for (int c = 0; c < CH; ++c) {
    size_t base = ((size_t)b * CH + c) * KK + k;   // coalesced across threads
    cnt += cnt_p[base]; den += den_p[base];
    cpc += cpc_p[base]; cpl += cpl_p[base];
    fc = min(fc, first_p[base]);
  }
  bool present = cnt > 0.f;
  bool vinst = present && (cpc == 1.0f);
  float p = __expf(cpl) / fmaxf(den, 1e-30f);
  seg_cnt[idx] = cnt;
  cpc_tot[idx] = cpc;
  loss_v[idx] = vinst ? -__logf(p + 1e-9f) : 0.f;
  valid_f[idx] = vinst ? 1.f : 0.f;
  has_cp_f[idx] = ((fc < NN) && present) ? 1.f : 0.f;
  d2_acc[idx] = 0.f;
  if (idx < BB) rep_acc[idx] = 0.f;
  if (idx == 0) *done = 0u;
  int row = fc < NN ? fc : NN - 1;
  const float4* src = (const float4*)(embed + ((size_t)b * NN + row) * DD);
  float4* dst = (float4*)(cp_emb + (size_t)idx * DD);
  #pragma unroll
  for (int q = 0; q < DD / 4; ++q) {
    float4 v = src[q];
    v.x = fixnum(v.x); v.y = fixnum(v.y); v.z = fixnum(v.z); v.w = fixnum(v.w);
    dst[q] = v;
  }
}

// ---- K3: attraction scan (coalesced, strided) + repulsion + last-block final ----
__global__ __launch_bounds__(TPB) void k3_attr_rep_fin(
    const float* __restrict__ embed, const int* __restrict__ sid,
    const float* __restrict__ cp_emb, const float* __restrict__ has_cp_f,
    const float* __restrict__ seg_cnt, const float* __restrict__ loss_v,
    const float* __restrict__ valid_f, const float* __restrict__ cpc_tot,
    const float* __restrict__ marg_p,
    float* __restrict__ d2_acc, float* __restrict__ rep_acc,
    unsigned* __restrict__ done, float* __restrict__ out)
{
  __shared__ float s_d2[KK];
  __shared__ float sred[4];
  __shared__ float s_b[BB][5];
  __shared__ int amLast;
  int b = blockIdx.x >> 6, c = blockIdx.x & 63, t = threadIdx.x;
  for (int k = t; k < KK; k += TPB) s_d2[k] = 0.f;
  __syncthreads();
  const float* cebase = cp_emb + (size_t)b * KK * DD;
  {
    size_t gb = (size_t)b * NN + c * HPB + t;
    int ss[4];
    #pragma unroll
    for (int i = 0; i < 4; ++i) ss[i] = sid[gb + i * TPB];  // coalesced, hoisted
    #pragma unroll
    for (int i = 0; i < 4; ++i) {
      size_t g = gb + i * TPB;
      const float4* e  = (const float4*)(embed + g * DD);   // lane-consecutive rows
      const float4* ce = (const float4*)(cebase + (size_t)ss[i] * DD);  // L1/L2-hot
      float d2 = 0.f;
      #pragma unroll
      for (int q = 0; q < DD / 4; ++q) {
        float4 ev = e[q]; float4 cv = ce[q];
        float x;
        x = fixnum(ev.x) - cv.x; d2 += x * x;
        x = fixnum(ev.y) - cv.y; d2 += x * x;
        x = fixnum(ev.z) - cv.z; d2 += x * x;
        x = fixnum(ev.w) - cv.w; d2 += x * x;
      }
      atomicAdd(&s_d2[ss[i]], fminf(d2, 50.f));
    }
  }
  __syncthreads();
  for (int k = t; k < KK; k += TPB)
    atomicAdd(&d2_acc[b * KK + k], s_d2[k]);   // device-scope atomics (coherent point)

  // --- repulsion: rows c*RPB..+RPB, cols j0=t, j1=t+TPB ---
  {
    int j0 = t, j1 = t + TPB;
    float cj0[DD], cj1[DD];
    const float4* cj0p = (const float4*)(cebase + (size_t)j0 * DD);
    const float4* cj1p = (const float4*)(cebase + (size_t)j1 * DD);
    #pragma unroll
    for (int q = 0; q < DD / 4; ++q) {
      float4 a = cj0p[q], bq = cj1p[q];
      cj0[q*4] = a.x; cj0[q*4+1] = a.y; cj0[q*4+2] = a.z; cj0[q*4+3] = a.w;
      cj1[q*4] = bq.x; cj1[q*4+1] = bq.y; cj1[q*4+2] = bq.z; cj1[q*4+3] = bq.w;
    }
    float m0 = has_cp_f[b * KK + j0], m1 = has_cp_f[b * KK + j1];
    float acc = 0.f;
    #pragma unroll
    for (int ri = 0; ri < RPB; ++ri) {
      int i = c * RPB + ri;
      float mi = has_cp_f[b * KK + i];        // uniform -> broadcast
      float d20 = 0.f, d21 = 0.f;
      #pragma unroll
      for (int d = 0; d < DD; ++d) {
        float ci = cebase[i * DD + d];        // uniform -> broadcast
        float x0 = ci - cj0[d]; d20 += x0 * x0;
        float x1 = ci - cj1[d]; d21 += x1 * x1;
      }
      acc += mi * (m0 * __expf(-fminf(d20, 50.f)) + m1 * __expf(-fminf(d21, 50.f)));
    }
    float tot = blockReduceSum(acc, sred);
    if (t == 0) atomicAdd(&rep_acc[b], tot);
  }

  // --- last-block finalize: relaxed ticket (no fences needed: all cross-block
  //     data moves via device-scope atomics; __syncthreads drains vmcnt first) ---
  __syncthreads();
  if (t == 0) {
    unsigned old = __hip_atomic_fetch_add(done, 1u, __ATOMIC_RELAXED,
                                          __HIP_MEMORY_SCOPE_AGENT);
    amLast = (old == (unsigned)(BB * CH - 1));
  }
  __syncthreads();
  if (amLast) {
    int w = t >> 6, l = t & 63;               // 4 waves x 4 batches each
    #pragma unroll
    for (int bb = 0; bb < 4; ++bb) {
      int fb = w * 4 + bb;
      float attr = 0.f, ce = 0.f, vcnt = 0.f, pcnt = 0.f, mcnt = 0.f;
      #pragma unroll
      for (int k = l; k < KK; k += 64) {
        int idx = fb * KK + k;
        float hc = has_cp_f[idx];
        float dv = __hip_atomic_load(&d2_acc[idx], __ATOMIC_RELAXED,
                                     __HIP_MEMORY_SCOPE_AGENT);
        attr += hc * (dv / fmaxf(seg_cnt[idx], 1.f));
        ce   += loss_v[idx];
        vcnt += valid_f[idx];
        pcnt += cpc_tot[idx];
        mcnt += hc;
      }
      float pm = marg_p[(fb * CH + l) * 2];     // CH==64 == lanes
      float nm = marg_p[(fb * CH + l) * 2 + 1];
      #pragma unroll
      for (int off = 32; off > 0; off >>= 1) {
        attr += __shfl_down(attr, off, 64);
        ce   += __shfl_down(ce, off, 64);
        vcnt += __shfl_down(vcnt, off, 64);
        pcnt += __shfl_down(pcnt, off, 64);
        mcnt += __shfl_down(mcnt, off, 64);
        pm   += __shfl_down(pm, off, 64);
        nm   += __shfl_down(nm, off, 64);
      }
      if (l == 0) {
        float pos = pcnt, neg = (float)NN - pos;
        float slice_ce = ce / fmaxf(vcnt, 1.f);
        float beta_loss = slice_ce + 5.0f * (pm / fmaxf(pos, 1.f) + nm / fmaxf(neg, 1.f));
        float repv = __hip_atomic_load(&rep_acc[fb], __ATOMIC_RELAXED,
                                       __HIP_MEMORY_SCOPE_AGENT);
        float rep = repv / fmaxf(mcnt * mcnt, 1.f);
        float repulsion = (mcnt > 1.f) ? 1.5f * rep : 0.f;
        float v = (pos >= 1.f && neg >= 1.f && vcnt > 0.f) ? 1.f : 0.f;
        s_b[fb][0] = (beta_loss + attr + repulsion) * v;
        s_b[fb][1] = beta_loss * v;
        s_b[fb][2] = attr * v;
        s_b[fb][3] = repulsion * v;
        s_b[fb][4] = v;
      }
    }
    __syncthreads();
    if (t == 0) {
      float s0 = 0.f, s1 = 0.f, s2 = 0.f, s3 = 0.f, cv = 0.f;
      #pragma unroll
      for (int i = 0; i < BB; ++i) {
        s0 += s_b[i][0]; s1 += s_b[i][1]; s2 += s_b[i][2]; s3 += s_b[i][3]; cv += s_b[i][4];
      }
      float safe = fmaxf(cv, 1.f);
      bool ok = cv > 0.f;
      out[0] = ok ? s0 / safe : 0.f;
      out[1] = ok ? s1 / safe : 0.f;
      out[2] = ok ? s2 / safe : 0.f;
      out[3] = ok ? s3 / safe : 0.f;
    }
  }
}

extern "C" void kernel_launch(void* const* d_in, const int* in_sizes, int n_in,
                              void* d_out, int out_size, void* d_ws, size_t ws_size,
                              hipStream_t stream) {
  (void)in_sizes; (void)n_in; (void)out_size; (void)ws_size;
  const float* beta  = (const float*)d_in[0];
  const float* embed = (const float*)d_in[1];
  const int*   sid   = (const int*)d_in[2];
  const int*   iscp  = (const int*)d_in[3];
  float* out = (float*)d_out;
  char* ws = (char*)d_ws;

  size_t off = 0;
  auto alloc = [&](size_t bytes) {
    size_t o = off; off += (bytes + 255) & ~(size_t)255; return o;
  };
  const size_t BCK = (size_t)BB * CH * KK * 4;   // 2 MB partial arrays
  const size_t BKf = (size_t)BB * KK * 4;        // 32 KB
  size_t o_cnt_p  = alloc(BCK);
  size_t o_den_p  = alloc(BCK);
  size_t o_cpc_p  = alloc(BCK);
  size_t o_cpl_p  = alloc(BCK);
  size_t o_first  = alloc(BCK);
  size_t o_marg   = alloc((size_t)BB * CH * 2 * 4);
  size_t o_segc   = alloc(BKf);
  size_t o_lossv  = alloc(BKf);
  size_t o_validf = alloc(BKf);
  size_t o_hascp  = alloc(BKf);
  size_t o_cpct   = alloc(BKf);
  size_t o_d2     = alloc(BKf);
  size_t o_cpe    = alloc((size_t)BB * KK * DD * 4);
  size_t o_rep    = alloc((size_t)BB * 4);
  size_t o_done   = alloc(256);

  k1_seg<<<BB * CH, TPB, 0, stream>>>(beta, sid, iscp,
      (float*)(ws + o_cnt_p), (float*)(ws + o_den_p),
      (float*)(ws + o_cpc_p), (float*)(ws + o_cpl_p),
      (int*)(ws + o_first), (float*)(ws + o_marg));

  k2_fin<<<(BB * KK) / TPB, TPB, 0, stream>>>(embed,
      (const float*)(ws + o_cnt_p), (const float*)(ws + o_den_p),
      (const float*)(ws + o_cpc_p), (const float*)(ws + o_cpl_p),
      (const int*)(ws + o_first),
      (float*)(ws + o_segc), (float*)(ws + o_lossv), (float*)(ws + o_validf),
      (float*)(ws + o_hascp), (float*)(ws + o_cpct), (float*)(ws + o_cpe),
      (float*)(ws + o_d2), (float*)(ws + o_rep), (unsigned*)(ws + o_done));

  k3_attr_rep_fin<<<BB * CH, TPB, 0, stream>>>(embed, sid,
      (const float*)(ws + o_cpe), (const float*)(ws + o_hascp),
      (const float*)(ws + o_segc), (const float*)(ws + o_lossv),
      (const float*)(ws + o_validf), (const float*)(ws + o_cpct),
      (const float*)(ws + o_marg),
      (float*)(ws + o_d2), (float*)(ws + o_rep),
      (unsigned*)(ws + o_done), out);
}